// Round 6
// baseline (25.798 us; speedup 1.0000x reference)
//
#include <hip/hip_runtime.h>
#include <math.h>

#define FDIM 14
#define HBINS 7
#define WBINS 7
#define NTHREADS 256   // 4 waves/block; one wave = one (roi, bh) output row = 14KB

typedef float floatx4 __attribute__((ext_vector_type(4)));

// Wave-per-(n,bh): each wave writes 7 cells x 2KB contiguous. 7168 waves total
// = 28 waves/CU in one generation (no wave churn). Lane owns float4 chunks
// {lane, lane+64} of each cell. Fast path (sh==sw==1, bh<6, in-grid ROI):
// bins 0..5 are single pixels -> 3-cell batches of independent loads/stores.
__global__ __launch_bounds__(NTHREADS) void roi_pool_kernel(
    const float* __restrict__ fm,    // [14, 14, 512]
    const float* __restrict__ rois,  // [N, 4]
    float* __restrict__ out,         // [N, 7, 7, 512]
    int njobs)                       // N * 7
{
    const int wid  = threadIdx.x >> 6;
    const int lane = threadIdx.x & 63;
    const int job  = blockIdx.x * (NTHREADS / 64) + wid;   // (n, bh)
    if (job >= njobs) return;
    const int n  = job / HBINS;
    const int bh = job - n * HBINS;

    const floatx4* fm4  = (const floatx4*)fm;
    floatx4*       out4 = (floatx4*)out;

    const floatx4 r = ((const floatx4*)rois)[n];
    const int x_min = (int)floorf((float)FDIM * r.x);
    const int y_min = (int)floorf((float)FDIM * r.y);
    const int x_max = (int)floorf((float)FDIM * r.z);
    const int y_max = (int)floorf((float)FDIM * r.w);
    const int rw = x_max - x_min;
    const int rh = y_max - y_min;
    const int sw = rw / WBINS;
    const int sh = rh / HBINS;

    // Row range for this bh (TF binning; sh==0 dumps all rows into bin 6).
    int r0, r1;
    if (sh > 0) { r0 = bh * sh; r1 = (bh < HBINS - 1) ? r0 + sh : rh; }
    else        { r0 = 0;       r1 = (bh == HBINS - 1) ? rh : 0; }
    r0 = max(r0, -y_min);  r1 = min(r1, FDIM - y_min);

    const size_t rowbase = (size_t)(n * (HBINS * WBINS) + bh * WBINS) * 128;
    const floatx4 NEGINF4 = { -INFINITY, -INFINITY, -INFINITY, -INFINITY };

    if (sh == 1 && sw == 1 && bh < HBINS - 1 &&
        x_min >= 0 && x_max < FDIM && r1 == r0 + 1) {
        // FAST PATH: single input row; bins 0..5 are exactly one pixel.
        const floatx4* row = fm4 + (size_t)((y_min + r0) * FDIM) * 128;
        #pragma unroll
        for (int half = 0; half < 2; ++half) {
            const int b0 = half * 3;
            floatx4 v[6];
            #pragma unroll
            for (int j = 0; j < 3; ++j) {
                const floatx4* px = row + (size_t)(x_min + b0 + j) * 128;
                v[2*j]   = px[lane];
                v[2*j+1] = px[lane + 64];
            }
            #pragma unroll
            for (int j = 0; j < 3; ++j) {
                out4[rowbase + (size_t)(b0 + j) * 128 + lane]      = v[2*j];
                out4[rowbase + (size_t)(b0 + j) * 128 + lane + 64] = v[2*j+1];
            }
        }
        // Last bin: single row, cols 6..rw-1 (in-grid by the guard above).
        floatx4 a0 = NEGINF4, a1 = NEGINF4;
        for (int rx = 6; rx < rw; ++rx) {
            const floatx4* px = row + (size_t)(x_min + rx) * 128;
            const floatx4 v0 = px[lane];
            const floatx4 v1 = px[lane + 64];
            a0.x = fmaxf(a0.x, v0.x);  a0.y = fmaxf(a0.y, v0.y);
            a0.z = fmaxf(a0.z, v0.z);  a0.w = fmaxf(a0.w, v0.w);
            a1.x = fmaxf(a1.x, v1.x);  a1.y = fmaxf(a1.y, v1.y);
            a1.z = fmaxf(a1.z, v1.z);  a1.w = fmaxf(a1.w, v1.w);
        }
        out4[rowbase + (size_t)6 * 128 + lane]      = a0;
        out4[rowbase + (size_t)6 * 128 + lane + 64] = a1;
    } else {
        // GENERIC PATH (bh==6, degenerate/clipped ROIs): per-cell loops.
        for (int bw = 0; bw < WBINS; ++bw) {
            int c0, c1;
            if (sw > 0) { c0 = bw * sw; c1 = (bw < WBINS - 1) ? c0 + sw : rw; }
            else        { c0 = 0;       c1 = (bw == WBINS - 1) ? rw : 0; }
            c0 = max(c0, -x_min);  c1 = min(c1, FDIM - x_min);

            floatx4 a0 = NEGINF4, a1 = NEGINF4;
            for (int ry = r0; ry < r1; ++ry) {
                const floatx4* row = fm4 + (size_t)((y_min + ry) * FDIM) * 128;
                for (int rx = c0; rx < c1; ++rx) {
                    const floatx4* px = row + (size_t)(x_min + rx) * 128;
                    const floatx4 v0 = px[lane];
                    const floatx4 v1 = px[lane + 64];
                    a0.x = fmaxf(a0.x, v0.x);  a0.y = fmaxf(a0.y, v0.y);
                    a0.z = fmaxf(a0.z, v0.z);  a0.w = fmaxf(a0.w, v0.w);
                    a1.x = fmaxf(a1.x, v1.x);  a1.y = fmaxf(a1.y, v1.y);
                    a1.z = fmaxf(a1.z, v1.z);  a1.w = fmaxf(a1.w, v1.w);
                }
            }
            out4[rowbase + (size_t)bw * 128 + lane]      = a0;
            out4[rowbase + (size_t)bw * 128 + lane + 64] = a1;
        }
    }
}

extern "C" void kernel_launch(void* const* d_in, const int* in_sizes, int n_in,
                              void* d_out, int out_size, void* d_ws, size_t ws_size,
                              hipStream_t stream) {
    const float* fm   = (const float*)d_in[0];   // [1, 14, 14, 512]
    const float* rois = (const float*)d_in[1];   // [1, N, 4]
    const int N = in_sizes[1] / 4;               // 1024

    float* out = (float*)d_out;                  // [N, 7, 7, 512]

    const int njobs  = N * HBINS;                         // 7168
    const int blocks = (njobs + (NTHREADS / 64) - 1) / (NTHREADS / 64);  // 1792
    roi_pool_kernel<<<blocks, NTHREADS, 0, stream>>>(fm, rois, out, njobs);
}

// Round 8
// 25.483 us; speedup vs baseline: 1.0123x; 1.0123x over previous
//
#include <hip/hip_runtime.h>
#include <math.h>

#define FDIM 14
#define HBINS 7
#define WBINS 7
#define NTHREADS 448   // 7 waves; wave wid = bin row bh; block = (roi n, channel half)

typedef float floatx4 __attribute__((ext_vector_type(4)));

static __device__ __forceinline__ floatx4 fmax4(floatx4 a, floatx4 b) {
    floatx4 o;
    o.x = fmaxf(a.x, b.x); o.y = fmaxf(a.y, b.y);
    o.z = fmaxf(a.z, b.z); o.w = fmaxf(a.w, b.w);
    return o;
}

// block = (n, half): n = blockIdx>>1 (scalar ROI decode), half picks channel
// chunks [half*64, half*64+64). Wave wid = bh handles one output row (7 cells,
// 7KB for its half). FAST PATH (sh==sw==1, single in-grid row, rw<=9): load all
// 9 row pixels up front with CLAMPED indices (branchless; dups harmless under
// max), then 7 stores. No register is overwritten after its store is issued;
// 9-deep load MLP per wave.
__global__ __launch_bounds__(NTHREADS) void roi_pool_kernel(
    const float* __restrict__ fm,    // [14, 14, 512]
    const float* __restrict__ rois,  // [N, 4]
    float* __restrict__ out)         // [N, 7, 7, 512]
{
    const int n    = blockIdx.x >> 1;
    const int half = blockIdx.x & 1;
    const int bh   = threadIdx.x >> 6;           // 0..6
    const int ch   = (half << 6) + (threadIdx.x & 63);  // float4 chunk in [0,128)

    const floatx4* fm4  = (const floatx4*)fm;
    floatx4*       out4 = (floatx4*)out;

    // Scalar ROI decode (n is blockIdx-derived).
    const floatx4 r = ((const floatx4*)rois)[n];
    const int x_min = (int)floorf((float)FDIM * r.x);
    const int y_min = (int)floorf((float)FDIM * r.y);
    const int x_max = (int)floorf((float)FDIM * r.z);
    const int y_max = (int)floorf((float)FDIM * r.w);
    const int rw = x_max - x_min;
    const int rh = y_max - y_min;
    const int sw = rw / WBINS;
    const int sh = rh / HBINS;

    // Row range for this bh (TF binning; sh==0 dumps all rows into bin 6).
    int r0, r1;
    if (sh > 0) { r0 = bh * sh; r1 = (bh < HBINS - 1) ? r0 + sh : rh; }
    else        { r0 = 0;       r1 = (bh == HBINS - 1) ? rh : 0; }
    r0 = max(r0, -y_min);  r1 = min(r1, FDIM - y_min);

    const size_t rowbase = (size_t)(n * (HBINS * WBINS) + bh * WBINS) * 128 + ch;

    const bool fast = (sh == 1) & (sw == 1) & (rw <= 9) &
                      (x_min >= 0) & (x_max < FDIM) &
                      (r1 == r0 + 1) & ((unsigned)(y_min + r0) < FDIM);

    if (fast) {
        // BUGFIX vs R7: include x_min in the row base (was loading cols 0..8).
        const floatx4* row = fm4 + ((size_t)((y_min + r0) * FDIM) + x_min) * 128 + ch;
        const int rl = rw - 1;   // clamp limit (>= 6)
        // All loads issued before any store; clamped tail indices dedupe safely.
        const floatx4 v0 = row[(size_t)0 * 128];
        const floatx4 v1 = row[(size_t)1 * 128];
        const floatx4 v2 = row[(size_t)2 * 128];
        const floatx4 v3 = row[(size_t)3 * 128];
        const floatx4 v4 = row[(size_t)4 * 128];
        const floatx4 v5 = row[(size_t)5 * 128];
        const floatx4 v6 = row[(size_t)6 * 128];
        const floatx4 v7 = row[(size_t)min(7, rl) * 128];
        const floatx4 v8 = row[(size_t)min(8, rl) * 128];

        out4[rowbase + 0 * 128] = v0;
        out4[rowbase + 1 * 128] = v1;
        out4[rowbase + 2 * 128] = v2;
        out4[rowbase + 3 * 128] = v3;
        out4[rowbase + 4 * 128] = v4;
        out4[rowbase + 5 * 128] = v5;
        out4[rowbase + 6 * 128] = fmax4(v6, fmax4(v7, v8));
    } else {
        // GENERIC PATH (bh==6 rows with rh>7, degenerate/clipped ROIs).
        const floatx4 NEGINF4 = { -INFINITY, -INFINITY, -INFINITY, -INFINITY };
        for (int bw = 0; bw < WBINS; ++bw) {
            int c0, c1;
            if (sw > 0) { c0 = bw * sw; c1 = (bw < WBINS - 1) ? c0 + sw : rw; }
            else        { c0 = 0;       c1 = (bw == WBINS - 1) ? rw : 0; }
            c0 = max(c0, -x_min);  c1 = min(c1, FDIM - x_min);

            floatx4 acc = NEGINF4;
            for (int ry = r0; ry < r1; ++ry) {
                const floatx4* row = fm4 + (size_t)((y_min + ry) * FDIM) * 128 + ch;
                for (int rx = c0; rx < c1; ++rx)
                    acc = fmax4(acc, row[(size_t)(x_min + rx) * 128]);
            }
            out4[rowbase + (size_t)bw * 128] = acc;
        }
    }
}

extern "C" void kernel_launch(void* const* d_in, const int* in_sizes, int n_in,
                              void* d_out, int out_size, void* d_ws, size_t ws_size,
                              hipStream_t stream) {
    const float* fm   = (const float*)d_in[0];   // [1, 14, 14, 512]
    const float* rois = (const float*)d_in[1];   // [1, N, 4]
    const int N = in_sizes[1] / 4;               // 1024

    float* out = (float*)d_out;                  // [N, 7, 7, 512]

    const int blocks = N * 2;                    // 2048 blocks x 448 threads
    roi_pool_kernel<<<blocks, NTHREADS, 0, stream>>>(fm, rois, out);
}

// Round 9
// 22.479 us; speedup vs baseline: 1.1477x; 1.1337x over previous
//
#include <hip/hip_runtime.h>
#include <math.h>

#define FDIM 14
#define HBINS 7
#define WBINS 7
#define CELLS_N (HBINS * WBINS)   // 49
#define NTHREADS 256              // 4 waves/block; wave = one output cell

typedef float floatx4 __attribute__((ext_vector_type(4)));

static __device__ __forceinline__ floatx4 fmax4(floatx4 a, floatx4 b) {
    floatx4 o;
    o.x = fmaxf(a.x, b.x); o.y = fmaxf(a.y, b.y);
    o.z = fmaxf(a.z, b.z); o.w = fmaxf(a.w, b.w);
    return o;
}

// Wave-per-cell (R4's winning body) at 256-thr blocks: 32 waves/CU (vs 28 at
// 448-thr) and finer co-scheduling granularity. cell is wave-uniform; the
// readfirstlane forces the ROI decode onto SALU/s_load exactly like a
// blockIdx-derived value.
__global__ __launch_bounds__(NTHREADS) void roi_pool_kernel(
    const float* __restrict__ fm,    // [14, 14, 512]
    const float* __restrict__ rois,  // [N, 4]
    float* __restrict__ out)         // [N, 7, 7, 512]
{
    const int lane = threadIdx.x & 63;
    // Global wave index == output cell; uniform per wave -> force scalar.
    const int cell = __builtin_amdgcn_readfirstlane(
        blockIdx.x * (NTHREADS / 64) + (threadIdx.x >> 6));

    const int n   = cell / CELLS_N;
    const int rem = cell - n * CELLS_N;
    const int bh  = rem / WBINS;
    const int bw  = rem - bh * WBINS;

    const floatx4* fm4  = (const floatx4*)fm;
    floatx4*       out4 = (floatx4*)out;

    // Scalar ROI decode.
    const floatx4 r = ((const floatx4*)rois)[n];
    const int x_min = (int)floorf((float)FDIM * r.x);
    const int y_min = (int)floorf((float)FDIM * r.y);
    const int x_max = (int)floorf((float)FDIM * r.z);
    const int y_max = (int)floorf((float)FDIM * r.w);
    const int rw = x_max - x_min;
    const int rh = y_max - y_min;
    const int sw = rw / WBINS;
    const int sh = rh / HBINS;

    // TF binning: row range for bh, col range for bw (sh==0 -> all in bin 6).
    int r0, r1, c0, c1;
    if (sh > 0) { r0 = bh * sh; r1 = (bh < HBINS - 1) ? r0 + sh : rh; }
    else        { r0 = 0;       r1 = (bh == HBINS - 1) ? rh : 0; }
    if (sw > 0) { c0 = bw * sw; c1 = (bw < WBINS - 1) ? c0 + sw : rw; }
    else        { c0 = 0;       c1 = (bw == WBINS - 1) ? rw : 0; }

    // Clip to feature-map grid.
    r0 = max(r0, -y_min);  r1 = min(r1, FDIM - y_min);
    c0 = max(c0, -x_min);  c1 = min(c1, FDIM - x_min);

    floatx4 acc0 = { -INFINITY, -INFINITY, -INFINITY, -INFINITY };
    floatx4 acc1 = acc0;

    for (int ry = r0; ry < r1; ++ry) {
        const floatx4* row = fm4 + (size_t)((y_min + ry) * FDIM) * 128;
        for (int rx = c0; rx < c1; ++rx) {
            const floatx4* px = row + (size_t)(x_min + rx) * 128;
            const floatx4 v0 = px[lane];
            const floatx4 v1 = px[lane + 64];
            acc0 = fmax4(acc0, v0);
            acc1 = fmax4(acc1, v1);
        }
    }

    const size_t cellbase = (size_t)cell * 128;
    out4[cellbase + lane]      = acc0;
    out4[cellbase + lane + 64] = acc1;
}

extern "C" void kernel_launch(void* const* d_in, const int* in_sizes, int n_in,
                              void* d_out, int out_size, void* d_ws, size_t ws_size,
                              hipStream_t stream) {
    const float* fm   = (const float*)d_in[0];   // [1, 14, 14, 512]
    const float* rois = (const float*)d_in[1];   // [1, N, 4]
    const int N = in_sizes[1] / 4;               // 1024

    float* out = (float*)d_out;                  // [N, 7, 7, 512]

    const int ncells = N * CELLS_N;              // 50176
    const int blocks = ncells / (NTHREADS / 64); // 12544 (divides exactly)
    roi_pool_kernel<<<blocks, NTHREADS, 0, stream>>>(fm, rois, out);
}